// Round 3
// baseline (234.786 us; speedup 1.0000x reference)
//
#include <hip/hip_runtime.h>
#include <hip/hip_bf16.h>

#define BB   16
#define CIN  256
#define COUT 256
#define WD   256
#define HH   64
#define WWS  64
#define NSP  4096      // HH*WWS
#define KW   9

typedef __attribute__((ext_vector_type(8))) short short8;
typedef __attribute__((ext_vector_type(4))) float f32x4;
typedef unsigned short ushort_t;

// workspace layout
#define S_BYTES (BB*CIN*4)                       // 16 KB
#define WT_OFF (S_BYTES)
#define WT_BYTES (BB*9*COUT*CIN*2)               // 18.87 MB
#define X_OFF (WT_OFF + WT_BYTES)
#define X_BYTES (BB*NSP*CIN*2)                   // 33.55 MB
#define WS_NEEDED ((size_t)(X_OFF + X_BYTES))

__device__ inline ushort_t f2bf(float f) {
    __hip_bfloat16 h = __float2bfloat16(f);
    return __builtin_bit_cast(ushort_t, h);
}

__device__ inline void gload_lds16(const ushort_t* g, ushort_t* l) {
    __builtin_amdgcn_global_load_lds(
        (const __attribute__((address_space(1))) void*)g,
        (__attribute__((address_space(3))) void*)l, 16, 0, 0);
}

// ---------------------------------------------------------------------------
// Kernel 1: style modulation
// ---------------------------------------------------------------------------
__global__ __launch_bounds__(256)
void style_kernel(const float* __restrict__ w,
                  const float* __restrict__ style_w,
                  const float* __restrict__ style_b,
                  float* __restrict__ s) {
    const int b  = blockIdx.x;
    const int ci = threadIdx.x;
    __shared__ float wsh[WD];
    wsh[ci] = w[b * WD + ci];
    __syncthreads();
    const float* row = style_w + ci * WD;
    float acc = style_b[ci];
    #pragma unroll 4
    for (int k = 0; k < WD; ++k) acc += wsh[k] * row[k];
    s[b * CIN + ci] = acc;
}

// ---------------------------------------------------------------------------
// Kernel 2: demodulated weights -> bf16, layout [b][tap][co][ci]
// ---------------------------------------------------------------------------
__global__ __launch_bounds__(256)
void wt_kernel(const float* __restrict__ cw, const float* __restrict__ s,
               const float* __restrict__ scale_p, ushort_t* __restrict__ wt) {
    const int co = blockIdx.x, b = blockIdx.y, ci = threadIdx.x;
    const float sv = s[b * CIN + ci] * scale_p[0];
    const float* cp = cw + ((size_t)co * CIN + ci) * KW;
    float v[9];
    float ss = 0.f;
    #pragma unroll
    for (int t = 0; t < 9; ++t) { v[t] = cp[t] * sv; ss += v[t] * v[t]; }
    #pragma unroll
    for (int off = 32; off > 0; off >>= 1) ss += __shfl_down(ss, off);
    __shared__ float red[4];
    if ((ci & 63) == 0) red[ci >> 6] = ss;
    __syncthreads();
    const float dm = rsqrtf(red[0] + red[1] + red[2] + red[3] + 1e-8f);
    #pragma unroll
    for (int t = 0; t < 9; ++t)
        wt[((size_t)(b * 9 + t) * COUT + co) * CIN + ci] = f2bf(v[t] * dm);
}

// ---------------------------------------------------------------------------
// Kernel 3: x NCHW fp32 -> NHWC bf16  (xo[b][sp][ci])
// ---------------------------------------------------------------------------
__global__ __launch_bounds__(256)
void xpose_kernel(const float* __restrict__ x, ushort_t* __restrict__ xo) {
    const int spt = blockIdx.x;
    const int cit = blockIdx.y;
    const int b   = blockIdx.z;
    const int t   = threadIdx.x;
    __shared__ ushort_t tile[64 * 68];
    const int sp0 = spt * 64, ci0 = cit * 64;
    {
        const int spq = t & 15, cil = t >> 4;
        #pragma unroll
        for (int i = 0; i < 4; ++i) {
            const int ci = cil + i * 16;
            const float4 v = *(const float4*)(x + ((size_t)(b * CIN + ci0 + ci)) * NSP + sp0 + spq * 4);
            tile[(spq * 4 + 0) * 68 + ci] = f2bf(v.x);
            tile[(spq * 4 + 1) * 68 + ci] = f2bf(v.y);
            tile[(spq * 4 + 2) * 68 + ci] = f2bf(v.z);
            tile[(spq * 4 + 3) * 68 + ci] = f2bf(v.w);
        }
    }
    __syncthreads();
    {
        const int g4 = t & 15, sp = t >> 4;
        #pragma unroll
        for (int i = 0; i < 4; ++i) {
            const int spp = sp + i * 16;
            uint2 v = *(const uint2*)&tile[spp * 68 + g4 * 4];
            *(uint2*)(xo + ((size_t)(b * NSP + sp0 + spp)) * CIN + ci0 + g4 * 4) = v;
        }
    }
}

// ---------------------------------------------------------------------------
// Kernel 4: implicit-GEMM conv via MFMA, v3.
//   512 blocks (16 b x 2 co-half x 16 ntile), 256 threads (4 waves 2Mx2N).
//   BM=128 co, BN=256 spatial (4 rows). Per-wave 64x128 -> acc[4][8].
//   2 blocks/CU co-resident (LDS 56.3KB, regs<=256) for barrier overlap.
//   A staged via global_load_lds into [3][128][32], XOR-quad swizzle.
// ---------------------------------------------------------------------------
__global__ __launch_bounds__(256, 2)
void conv_mfma_kernel(const ushort_t* __restrict__ wt,   // [b][9][256][256]
                      const ushort_t* __restrict__ xo,   // [b][4096][256]
                      float* __restrict__ out) {
    const int wg = blockIdx.x;                 // 0..511
    const int b  = (wg & 7) + 8 * ((wg >> 3) & 1);   // batch pinned per XCD
    const int r2 = wg >> 4;                    // 0..31
    const int cohalf = r2 & 1;
    const int ntile  = r2 >> 1;                // 0..15
    const int y0 = ntile * 4;

    const int tid  = threadIdx.x;
    const int lane = tid & 63;
    const int w    = tid >> 6;                 // wave 0..3
    const int wm   = w >> 1;                   // co 64-half within 128
    const int wn   = w & 1;                    // spatial 128-half (2 rows)
    const int l15  = lane & 15;
    const int lg   = lane >> 4;

    __shared__ __align__(16) ushort_t lds_a[3 * 128 * 32];   // 24576 B
    __shared__ __align__(16) ushort_t lds_x[6 * 66 * 40];    // 31680 B

    // ---- A-DMA per-thread constants (2 gload_lds16 per step) ----
    // call i: row co_loc = i*64 + w*16 + (lane>>2), source quad pre-swizzled
    const int srcq = (lane & 3) ^ ((lane >> 3) & 3);         // involution
    long a_ginv[2];
    int  a_luni[2];                                          // wave-uniform
    #pragma unroll
    for (int i = 0; i < 2; ++i) {
        const int co_loc = i * 64 + w * 16 + (lane >> 2);
        a_ginv[i] = (long)(cohalf * 128 + co_loc) * CIN + srcq * 8;
        a_luni[i] = i * 2048 + w * 512;                      // ushorts
    }
    const long wtb = (long)b * 9 * COUT * CIN;

    // ---- x staging per-thread constants (6 tasks: rows 0..5) ----
    const int xc = w * 16 + l15;               // column 0..63 (conflict-free map)
    const int xg = lg;                         // ci quad 0..3
    int  x_lw[6]; long x_gb[6]; bool x_val[6];
    #pragma unroll
    for (int i = 0; i < 6; ++i) {
        const int y = y0 - 1 + i;
        x_val[i] = (y >= 0 && y < HH);
        const int yc = y < 0 ? 0 : (y > HH - 1 ? HH - 1 : y);
        x_lw[i] = (i * 66 + xc + 1) * 40 + xg * 8;
        x_gb[i] = ((long)(b * NSP + yc * WWS + xc)) * CIN + xg * 8;
    }

    // ---- fragment read bases ----
    const int aq8   = (lg ^ ((l15 >> 1) & 3)) * 8;           // read-side swizzle
    const int abase = (wm * 64 + l15) * 32 + aq8;            // + mi*512 + buf*4096
    // bf: row = wn*2 + (ni>>2) + ky, col = (ni&3)*16 + l15 + kx

    f32x4 acc[4][8];
    #pragma unroll
    for (int mi = 0; mi < 4; ++mi)
        #pragma unroll
        for (int ni = 0; ni < 8; ++ni) acc[mi][ni] = (f32x4){0.f, 0.f, 0.f, 0.f};

    // zero halo columns 0 and 65 (persist across chunks)
    if (tid < 60) {
        const int r = tid / 10, rem = tid % 10;
        const int c = (rem >= 5) ? 65 : 0, q = rem % 5;
        *(uint4*)&lds_x[(r * 66 + c) * 40 + q * 8] = make_uint4(0, 0, 0, 0);
    }

    // ---- prologue: x chunk0 -> regs; A-DMA for t=0 (buf0) and t=1 (buf1) ----
    uint4 rX[6];
    #pragma unroll
    for (int i = 0; i < 6; ++i)
        rX[i] = x_val[i] ? *(const uint4*)(xo + x_gb[i]) : make_uint4(0, 0, 0, 0);
    #pragma unroll
    for (int i = 0; i < 2; ++i) {
        gload_lds16(wt + wtb + 0L * COUT * CIN + 0 * 32 + a_ginv[i],
                    lds_a + 0 * 4096 + a_luni[i]);                      // t=0
        gload_lds16(wt + wtb + 1L * COUT * CIN + 0 * 32 + a_ginv[i],
                    lds_a + 1 * 4096 + a_luni[i]);                      // t=1
    }

    for (int chunk = 0; chunk < 8; ++chunk) {
        __syncthreads();                       // prev-chunk x readers done
        #pragma unroll
        for (int i = 0; i < 6; ++i) *(uint4*)&lds_x[x_lw[i]] = rX[i];
        __syncthreads();                       // x tile + pending A-DMA visible

        #pragma unroll
        for (int tap = 0; tap < 9; ++tap) {
            if (tap > 0) __syncthreads();      // A buffer rotation barrier

            // issue A-DMA for step t+2 into buf (tap+2)%3  (9%3==0 => static)
            {
                const int t2 = chunk * 9 + tap + 2;
                if (t2 < 72) {
                    const int tap2 = (tap + 2) % 9 + (tap == 6 ? 0 : 0); // = t2%9
                    const int tp2  = t2 % 9;
                    const int ch2  = t2 / 9;
                    const long goff = wtb + (long)tp2 * COUT * CIN + ch2 * 32;
                    ushort_t* lbase = lds_a + ((tap + 2) % 3) * 4096;
                    (void)tap2;
                    #pragma unroll
                    for (int i = 0; i < 2; ++i)
                        gload_lds16(wt + goff + a_ginv[i], lbase + a_luni[i]);
                }
            }
            // prefetch next chunk's x mid-chunk
            if (tap == 3 && chunk < 7) {
                #pragma unroll
                for (int i = 0; i < 6; ++i)
                    rX[i] = x_val[i] ? *(const uint4*)(xo + x_gb[i] + (chunk + 1) * 32)
                                     : make_uint4(0, 0, 0, 0);
            }

            const int ky = tap / 3, kx = tap % 3;
            const ushort_t* ab = lds_a + (tap % 3) * 4096 + abase;
            short8 af[4];
            #pragma unroll
            for (int mi = 0; mi < 4; ++mi) af[mi] = *(const short8*)(ab + mi * 512);
            short8 bf[8];
            #pragma unroll
            for (int ni = 0; ni < 8; ++ni) {
                const int row = wn * 2 + (ni >> 2) + ky;
                const int col = (ni & 3) * 16 + l15 + kx;
                bf[ni] = *(const short8*)(lds_x + (row * 66 + col) * 40 + lg * 8);
            }
            __builtin_amdgcn_s_setprio(1);
            #pragma unroll
            for (int mi = 0; mi < 4; ++mi)
                #pragma unroll
                for (int ni = 0; ni < 8; ++ni)
                    acc[mi][ni] = __builtin_amdgcn_mfma_f32_16x16x32_bf16(
                        af[mi], bf[ni], acc[mi][ni], 0, 0, 0);
            __builtin_amdgcn_s_setprio(0);
        }
    }

    // ---- epilogue: C frag row=co=(lane>>4)*4+reg, col=sp=lane&15 ----
    const int co_b = cohalf * 128 + wm * 64 + lg * 4;
    const int sp_b = ntile * 256 + wn * 128 + l15;
    #pragma unroll
    for (int mi = 0; mi < 4; ++mi)
        #pragma unroll
        for (int ni = 0; ni < 8; ++ni)
            #pragma unroll
            for (int rg = 0; rg < 4; ++rg) {
                const int co = co_b + mi * 16 + rg;
                const int sp = sp_b + ni * 16;
                out[((long)(b * COUT + co)) * NSP + sp] = acc[mi][ni][rg];
            }
}

// ---------------------------------------------------------------------------
// Fallback fp32 direct conv if workspace is too small.
// ---------------------------------------------------------------------------
__global__ __launch_bounds__(256)
void modconv_kernel(const float* __restrict__ x,
                    const float* __restrict__ cw,
                    const float* __restrict__ s,
                    const float* __restrict__ scale_p,
                    float* __restrict__ out) {
    const int tile = blockIdx.x;
    const int co   = blockIdx.y;
    const int b    = blockIdx.z;
    const int tid  = threadIdx.x;
    const float scale = scale_p[0];

    __shared__ float s_wt[CIN * KW];
    __shared__ float s_x[18 * 66];
    __shared__ float red[4];

    const float* cwb = cw + (size_t)co * CIN * KW;
    const float* sb  = s + b * CIN;
    float sumsq = 0.f;
    for (int i = tid; i < CIN * KW; i += 256) {
        float v = cwb[i] * scale * sb[i / KW];
        s_wt[i] = v;
        sumsq += v * v;
    }
    #pragma unroll
    for (int off = 32; off > 0; off >>= 1) sumsq += __shfl_down(sumsq, off);
    if ((tid & 63) == 0) red[tid >> 6] = sumsq;
    __syncthreads();
    const float demod = rsqrtf(red[0] + red[1] + red[2] + red[3] + 1e-8f);
    for (int i = tid; i < CIN * KW; i += 256) s_wt[i] *= demod;

    const int tx = tid & 63;
    const int tr = tid >> 6;
    const int y0 = tile * 16;
    float acc[4] = {0.f, 0.f, 0.f, 0.f};

    for (int ci = 0; ci < CIN; ++ci) {
        __syncthreads();
        const float* xb = x + ((size_t)(b * CIN + ci)) * (HH * WWS);
        for (int idx = tid; idx < 18 * 66; idx += 256) {
            const int r = idx / 66, c = idx % 66;
            const int yg = y0 - 1 + r, xg = c - 1;
            float v = 0.f;
            if (yg >= 0 && yg < HH && xg >= 0 && xg < WWS) v = xb[yg * WWS + xg];
            s_x[idx] = v;
        }
        __syncthreads();
        const float* wr = s_wt + ci * KW;
        const float w0 = wr[0], w1 = wr[1], w2 = wr[2];
        const float w3 = wr[3], w4 = wr[4], w5 = wr[5];
        const float w6 = wr[6], w7 = wr[7], w8 = wr[8];
        const int rbase = tr * 4;
        float xv[6][3];
        #pragma unroll
        for (int j = 0; j < 6; ++j)
            #pragma unroll
            for (int k = 0; k < 3; ++k) xv[j][k] = s_x[(rbase + j) * 66 + tx + k];
        #pragma unroll
        for (int i = 0; i < 4; ++i)
            acc[i] += w0 * xv[i][0] + w1 * xv[i][1] + w2 * xv[i][2]
                    + w3 * xv[i+1][0] + w4 * xv[i+1][1] + w5 * xv[i+1][2]
                    + w6 * xv[i+2][0] + w7 * xv[i+2][1] + w8 * xv[i+2][2];
    }
    float* ob = out + (((size_t)(b * COUT + co)) * HH + y0) * WWS + tx;
    #pragma unroll
    for (int i = 0; i < 4; ++i) ob[(tr * 4 + i) * WWS] = acc[i];
}

// ---------------------------------------------------------------------------
extern "C" void kernel_launch(void* const* d_in, const int* in_sizes, int n_in,
                              void* d_out, int out_size, void* d_ws, size_t ws_size,
                              hipStream_t stream) {
    const float* x       = (const float*)d_in[0];
    const float* w       = (const float*)d_in[1];
    const float* cw      = (const float*)d_in[2];
    const float* style_w = (const float*)d_in[3];
    const float* style_b = (const float*)d_in[4];
    const float* scale_p = (const float*)d_in[5];
    float*       out     = (float*)d_out;

    float*    s    = (float*)d_ws;
    ushort_t* wswt = (ushort_t*)((char*)d_ws + WT_OFF);
    ushort_t* wsx  = (ushort_t*)((char*)d_ws + X_OFF);

    style_kernel<<<dim3(BB), 256, 0, stream>>>(w, style_w, style_b, s);

    if (ws_size >= WS_NEEDED) {
        wt_kernel<<<dim3(COUT, BB), 256, 0, stream>>>(cw, s, scale_p, wswt);
        xpose_kernel<<<dim3(64, 4, BB), 256, 0, stream>>>(x, wsx);
        conv_mfma_kernel<<<dim3(512), 256, 0, stream>>>(wswt, wsx, out);
    } else {
        modconv_kernel<<<dim3(4, COUT, BB), 256, 0, stream>>>(x, cw, s, scale_p, out);
    }
}

// Round 4
// 108.720 us; speedup vs baseline: 2.1595x; 2.1595x over previous
//
#include <hip/hip_runtime.h>
#include <hip/hip_bf16.h>

#define BB   16
#define CIN  256
#define COUT 256
#define WD   256
#define HH   64
#define WWS  64
#define NSP  4096      // HH*WWS
#define KW   9

typedef __attribute__((ext_vector_type(8))) short short8;
typedef __attribute__((ext_vector_type(4))) float f32x4;
typedef unsigned short ushort_t;

// workspace layout
#define S_BYTES (BB*CIN*4)                       // 16 KB
#define WT_OFF (S_BYTES)
#define WT_BYTES (BB*9*COUT*CIN*2)               // 18.87 MB
#define X_OFF (WT_OFF + WT_BYTES)
#define X_BYTES (BB*NSP*CIN*2)                   // 33.55 MB
#define ZP_OFF (X_OFF + X_BYTES)
#define ZP_BYTES 4096
#define WS_NEEDED ((size_t)(ZP_OFF + ZP_BYTES))

#define WAITVM2 asm volatile("s_waitcnt vmcnt(2)" ::: "memory")
#define WAITVM8 asm volatile("s_waitcnt vmcnt(8)" ::: "memory")

__device__ inline ushort_t f2bf(float f) {
    __hip_bfloat16 h = __float2bfloat16(f);
    return __builtin_bit_cast(ushort_t, h);
}

__device__ inline void gload_lds16(const ushort_t* g, ushort_t* l) {
    __builtin_amdgcn_global_load_lds(
        (const __attribute__((address_space(1))) void*)g,
        (__attribute__((address_space(3))) void*)l, 16, 0, 0);
}

// ---------------------------------------------------------------------------
// Kernel 0: zero page for OOB x rows
// ---------------------------------------------------------------------------
__global__ __launch_bounds__(256)
void zero_kernel(float* __restrict__ zp) {
    ((float4*)zp)[threadIdx.x] = make_float4(0.f, 0.f, 0.f, 0.f);
}

// ---------------------------------------------------------------------------
// Kernel 1: style modulation
// ---------------------------------------------------------------------------
__global__ __launch_bounds__(256)
void style_kernel(const float* __restrict__ w,
                  const float* __restrict__ style_w,
                  const float* __restrict__ style_b,
                  float* __restrict__ s) {
    const int b  = blockIdx.x;
    const int ci = threadIdx.x;
    __shared__ float wsh[WD];
    wsh[ci] = w[b * WD + ci];
    __syncthreads();
    const float* row = style_w + ci * WD;
    float acc = style_b[ci];
    #pragma unroll 4
    for (int k = 0; k < WD; ++k) acc += wsh[k] * row[k];
    s[b * CIN + ci] = acc;
}

// ---------------------------------------------------------------------------
// Kernel 2: demodulated weights -> bf16, layout [b][tap][co][ci]
// ---------------------------------------------------------------------------
__global__ __launch_bounds__(256)
void wt_kernel(const float* __restrict__ cw, const float* __restrict__ s,
               const float* __restrict__ scale_p, ushort_t* __restrict__ wt) {
    const int co = blockIdx.x, b = blockIdx.y, ci = threadIdx.x;
    const float sv = s[b * CIN + ci] * scale_p[0];
    const float* cp = cw + ((size_t)co * CIN + ci) * KW;
    float v[9];
    float ss = 0.f;
    #pragma unroll
    for (int t = 0; t < 9; ++t) { v[t] = cp[t] * sv; ss += v[t] * v[t]; }
    #pragma unroll
    for (int off = 32; off > 0; off >>= 1) ss += __shfl_down(ss, off);
    __shared__ float red[4];
    if ((ci & 63) == 0) red[ci >> 6] = ss;
    __syncthreads();
    const float dm = rsqrtf(red[0] + red[1] + red[2] + red[3] + 1e-8f);
    #pragma unroll
    for (int t = 0; t < 9; ++t)
        wt[((size_t)(b * 9 + t) * COUT + co) * CIN + ci] = f2bf(v[t] * dm);
}

// ---------------------------------------------------------------------------
// Kernel 3: x NCHW fp32 -> NHWC bf16  (xo[b][sp][ci])
// ---------------------------------------------------------------------------
__global__ __launch_bounds__(256)
void xpose_kernel(const float* __restrict__ x, ushort_t* __restrict__ xo) {
    const int spt = blockIdx.x;
    const int cit = blockIdx.y;
    const int b   = blockIdx.z;
    const int t   = threadIdx.x;
    __shared__ ushort_t tile[64 * 68];
    const int sp0 = spt * 64, ci0 = cit * 64;
    {
        const int spq = t & 15, cil = t >> 4;
        #pragma unroll
        for (int i = 0; i < 4; ++i) {
            const int ci = cil + i * 16;
            const float4 v = *(const float4*)(x + ((size_t)(b * CIN + ci0 + ci)) * NSP + sp0 + spq * 4);
            tile[(spq * 4 + 0) * 68 + ci] = f2bf(v.x);
            tile[(spq * 4 + 1) * 68 + ci] = f2bf(v.y);
            tile[(spq * 4 + 2) * 68 + ci] = f2bf(v.z);
            tile[(spq * 4 + 3) * 68 + ci] = f2bf(v.w);
        }
    }
    __syncthreads();
    {
        const int g4 = t & 15, sp = t >> 4;
        #pragma unroll
        for (int i = 0; i < 4; ++i) {
            const int spp = sp + i * 16;
            uint2 v = *(const uint2*)&tile[spp * 68 + g4 * 4];
            *(uint2*)(xo + ((size_t)(b * NSP + sp0 + spp)) * CIN + ci0 + g4 * 4) = v;
        }
    }
}

// ---------------------------------------------------------------------------
// Kernel 4: implicit-GEMM conv, counted-vmcnt pipelined schedule.
//   512 blocks (16 b x 2 cohalf x 16 ntile), 256 threads (4 waves 2Mx2N).
//   BM=128 co, BN=256 sp (4 rows). Per-wave 64x128 -> acc[4][8].
//   A: [3][128][32] triple-buffer via global_load_lds, issued 2 steps ahead.
//   x: [2][6][66][32] double-buffer via global_load_lds, issued 9 steps ahead
//      (OOB rows sourced from a zeroed ws page; halo cols 0/65 zeroed once).
//   XOR quad-swizzle key=(v^(v>>2))&3 on both DMA source and LDS reads.
//   Raw s_barrier + counted vmcnt (2 steady / 8 after x-issue), never 0.
// ---------------------------------------------------------------------------
__global__ __launch_bounds__(256, 2)
void conv_mfma_kernel(const ushort_t* __restrict__ wt,   // [b][9][256][256]
                      const ushort_t* __restrict__ xo,   // [b][4096][256]
                      const ushort_t* __restrict__ zp,   // zero page
                      float* __restrict__ out) {
    const int wg = blockIdx.x;                 // 0..511
    const int b  = (wg & 7) + 8 * ((wg >> 3) & 1);   // batch pinned per XCD
    const int cohalf = (wg >> 4) & 1;
    const int ntile  = wg >> 5;                // 0..15
    const int y0 = ntile * 4;

    const int tid  = threadIdx.x;
    const int lane = tid & 63;
    const int w    = tid >> 6;                 // wave 0..3
    const int wm   = w >> 1;                   // co 64-half within 128
    const int wn   = w & 1;                    // spatial 128-half (2 rows)
    const int l15  = lane & 15;
    const int lg   = lane >> 4;                // 0..3 (ci quad)
    const int q    = lane >> 2;                // 0..15 (row-within-call)

    __shared__ __align__(16) ushort_t lds_a[3 * 128 * 32];       // 24576 B
    __shared__ __align__(16) ushort_t lds_x[2 * 6 * 66 * 32];    // 50688 B

    // ---- DMA source swizzle (involution key on 16B quads) ----
    const int srcq8 = (((lane & 3) ^ ((q ^ (q >> 2)) & 3))) * 8;

    // A: 2 calls/thread/step. Call i: rows i*64 + w*16 + q.
    const long wtb = (long)b * 9 * COUT * CIN;
    const ushort_t* pa0 = wt + wtb + (long)(cohalf * 128 + w * 16 + q) * CIN + srcq8;
    const ushort_t* pa1 = pa0 + 64 * CIN;
    const int aluni0 = w * 512;                // LDS ushort offset, wave-uniform
    const int aluni1 = 2048 + w * 512;

    // x: 6 calls/thread per chunk. Slot s = w*6+j: r=s>>2, cq=s&3.
    const ushort_t* px[6];
    int xdst_off[6];
    #pragma unroll
    for (int j = 0; j < 6; ++j) {
        const int s  = w * 6 + j;
        const int r  = s >> 2;
        const int cq = s & 3;
        const int y  = y0 - 1 + r;
        const bool val = (y >= 0 && y < HH);
        const int cp = cq * 16 + q;            // source spatial col 0..63
        px[j] = val ? (xo + ((long)b * NSP + (long)y * WWS + cp) * CIN + srcq8)
                    : (zp + lane * 8);
        xdst_off[j] = r * 2112 + cq * 512 + 32;   // +32: col-0 halo skip
    }

    // ---- fragment read slot swizzles ----
    const int slotA8 = (lg ^ ((l15 ^ (l15 >> 2)) & 3)) * 8;
    int slotB8[3];
    #pragma unroll
    for (int kx = 0; kx < 3; ++kx) {
        int c2 = l15 + kx - 1;
        if (c2 < 0) c2 = 0;                    // halo col: all-zero, any slot
        slotB8[kx] = (lg ^ ((c2 ^ (c2 >> 2)) & 3)) * 8;
    }
    const int abase = (wm * 64 + l15) * 32 + slotA8;

    f32x4 acc[4][8];
    #pragma unroll
    for (int mi = 0; mi < 4; ++mi)
        #pragma unroll
        for (int ni = 0; ni < 8; ++ni) acc[mi][ni] = (f32x4){0.f, 0.f, 0.f, 0.f};

    // ---- zero halo columns (cols 0 and 65) of both x buffers, once ----
    if (tid < 96) {
        const int cell = tid >> 2, qq = tid & 3;
        const int buf = cell / 12, cr = cell % 12;
        const int r = cr >> 1, col = (cr & 1) * 65;
        *(uint4*)&lds_x[buf * 12672 + r * 2112 + col * 32 + qq * 8] =
            make_uint4(0, 0, 0, 0);
    }

    // ---- prologue DMAs: x(chunk0)->xbuf0 [6], A(t=0)->buf0 [2], A(t=1)->buf1 [2]
    #pragma unroll
    for (int j = 0; j < 6; ++j)
        gload_lds16(px[j], lds_x + xdst_off[j]);
    gload_lds16(pa0, lds_a + aluni0);
    gload_lds16(pa1, lds_a + aluni1);
    gload_lds16(pa0 + (long)COUT * CIN, lds_a + 4096 + aluni0);
    gload_lds16(pa1 + (long)COUT * CIN, lds_a + 4096 + aluni1);

    asm volatile("s_waitcnt lgkmcnt(0)" ::: "memory");   // halo ds_writes done

    for (int chunk = 0; chunk < 8; ++chunk) {
        const ushort_t* xb = lds_x + (chunk & 1) * 12672;

        #pragma unroll
        for (int tap = 0; tap < 9; ++tap) {
            // ---- counted wait + barrier: A(t) ready, never drain to 0 ----
            if (tap == 1 || tap == 2) { WAITVM8; } else { WAITVM2; }
            __builtin_amdgcn_sched_barrier(0);
            __builtin_amdgcn_s_barrier();

            // ---- issue A-DMA for step t+2 (dummy wrap at tail) ----
            {
                const int tp2 = (tap + 2) % 9;
                const int ch2 = (tap >= 7) ? ((chunk + 1) & 7) : chunk;
                const long aoff = (long)tp2 * (COUT * CIN) + ch2 * 32;
                ushort_t* adst = lds_a + ((tap + 2) % 3) * 4096;
                gload_lds16(pa0 + aoff, adst + aluni0);
                gload_lds16(pa1 + aoff, adst + aluni1);
            }
            // ---- issue x-DMA for next chunk at tap 0 (dummy wrap at tail) --
            if (tap == 0) {
                const int cs = (chunk + 1) & 7;
                ushort_t* xdst = lds_x + ((chunk + 1) & 1) * 12672;
                #pragma unroll
                for (int j = 0; j < 6; ++j)
                    gload_lds16(px[j] + cs * 32, xdst + xdst_off[j]);
            }

            // ---- fragment reads ----
            const int ky = tap / 3, kx = tap % 3;
            const ushort_t* ab = lds_a + (tap % 3) * 4096 + abase;
            short8 af[4];
            #pragma unroll
            for (int mi = 0; mi < 4; ++mi) af[mi] = *(const short8*)(ab + mi * 512);
            short8 bf[8];
            #pragma unroll
            for (int ni = 0; ni < 8; ++ni) {
                const int row = wn * 2 + (ni >> 2) + ky;
                const int col = (ni & 3) * 16 + l15 + kx;
                bf[ni] = *(const short8*)(xb + row * 2112 + col * 32 + slotB8[kx]);
            }

            // ---- 32 MFMA ----
            __builtin_amdgcn_s_setprio(1);
            #pragma unroll
            for (int mi = 0; mi < 4; ++mi)
                #pragma unroll
                for (int ni = 0; ni < 8; ++ni)
                    acc[mi][ni] = __builtin_amdgcn_mfma_f32_16x16x32_bf16(
                        af[mi], bf[ni], acc[mi][ni], 0, 0, 0);
            __builtin_amdgcn_s_setprio(0);
        }
    }

    // ---- epilogue: C frag row=co=(lane>>4)*4+reg, col=sp=lane&15 ----
    const int co_b = cohalf * 128 + wm * 64 + lg * 4;
    const int sp_b = ntile * 256 + wn * 128 + l15;
    #pragma unroll
    for (int mi = 0; mi < 4; ++mi)
        #pragma unroll
        for (int ni = 0; ni < 8; ++ni)
            #pragma unroll
            for (int rg = 0; rg < 4; ++rg) {
                const int co = co_b + mi * 16 + rg;
                const int sp = sp_b + ni * 16;
                out[((long)(b * COUT + co)) * NSP + sp] = acc[mi][ni][rg];
            }
}

// ---------------------------------------------------------------------------
// Fallback fp32 direct conv if workspace is too small.
// ---------------------------------------------------------------------------
__global__ __launch_bounds__(256)
void modconv_kernel(const float* __restrict__ x,
                    const float* __restrict__ cw,
                    const float* __restrict__ s,
                    const float* __restrict__ scale_p,
                    float* __restrict__ out) {
    const int tile = blockIdx.x;
    const int co   = blockIdx.y;
    const int b    = blockIdx.z;
    const int tid  = threadIdx.x;
    const float scale = scale_p[0];

    __shared__ float s_wt[CIN * KW];
    __shared__ float s_x[18 * 66];
    __shared__ float red[4];

    const float* cwb = cw + (size_t)co * CIN * KW;
    const float* sb  = s + b * CIN;
    float sumsq = 0.f;
    for (int i = tid; i < CIN * KW; i += 256) {
        float v = cwb[i] * scale * sb[i / KW];
        s_wt[i] = v;
        sumsq += v * v;
    }
    #pragma unroll
    for (int off = 32; off > 0; off >>= 1) sumsq += __shfl_down(sumsq, off);
    if ((tid & 63) == 0) red[tid >> 6] = sumsq;
    __syncthreads();
    const float demod = rsqrtf(red[0] + red[1] + red[2] + red[3] + 1e-8f);
    for (int i = tid; i < CIN * KW; i += 256) s_wt[i] *= demod;

    const int tx = tid & 63;
    const int tr = tid >> 6;
    const int y0 = tile * 16;
    float acc[4] = {0.f, 0.f, 0.f, 0.f};

    for (int ci = 0; ci < CIN; ++ci) {
        __syncthreads();
        const float* xb = x + ((size_t)(b * CIN + ci)) * (HH * WWS);
        for (int idx = tid; idx < 18 * 66; idx += 256) {
            const int r = idx / 66, c = idx % 66;
            const int yg = y0 - 1 + r, xg = c - 1;
            float v = 0.f;
            if (yg >= 0 && yg < HH && xg >= 0 && xg < WWS) v = xb[yg * WWS + xg];
            s_x[idx] = v;
        }
        __syncthreads();
        const float* wr = s_wt + ci * KW;
        const float w0 = wr[0], w1 = wr[1], w2 = wr[2];
        const float w3 = wr[3], w4 = wr[4], w5 = wr[5];
        const float w6 = wr[6], w7 = wr[7], w8 = wr[8];
        const int rbase = tr * 4;
        float xv[6][3];
        #pragma unroll
        for (int j = 0; j < 6; ++j)
            #pragma unroll
            for (int k = 0; k < 3; ++k) xv[j][k] = s_x[(rbase + j) * 66 + tx + k];
        #pragma unroll
        for (int i = 0; i < 4; ++i)
            acc[i] += w0 * xv[i][0] + w1 * xv[i][1] + w2 * xv[i][2]
                    + w3 * xv[i+1][0] + w4 * xv[i+1][1] + w5 * xv[i+1][2]
                    + w6 * xv[i+2][0] + w7 * xv[i+2][1] + w8 * xv[i+2][2];
    }
    float* ob = out + (((size_t)(b * COUT + co)) * HH + y0) * WWS + tx;
    #pragma unroll
    for (int i = 0; i < 4; ++i) ob[(tr * 4 + i) * WWS] = acc[i];
}

// ---------------------------------------------------------------------------
extern "C" void kernel_launch(void* const* d_in, const int* in_sizes, int n_in,
                              void* d_out, int out_size, void* d_ws, size_t ws_size,
                              hipStream_t stream) {
    const float* x       = (const float*)d_in[0];
    const float* w       = (const float*)d_in[1];
    const float* cw      = (const float*)d_in[2];
    const float* style_w = (const float*)d_in[3];
    const float* style_b = (const float*)d_in[4];
    const float* scale_p = (const float*)d_in[5];
    float*       out     = (float*)d_out;

    float*    s    = (float*)d_ws;
    ushort_t* wswt = (ushort_t*)((char*)d_ws + WT_OFF);
    ushort_t* wsx  = (ushort_t*)((char*)d_ws + X_OFF);
    float*    zp   = (float*)((char*)d_ws + ZP_OFF);

    style_kernel<<<dim3(BB), 256, 0, stream>>>(w, style_w, style_b, s);

    if (ws_size >= WS_NEEDED) {
        zero_kernel<<<dim3(1), 256, 0, stream>>>(zp);
        wt_kernel<<<dim3(COUT, BB), 256, 0, stream>>>(cw, s, scale_p, wswt);
        xpose_kernel<<<dim3(64, 4, BB), 256, 0, stream>>>(x, wsx);
        conv_mfma_kernel<<<dim3(512), 256, 0, stream>>>(wswt, wsx,
                                                        (const ushort_t*)zp, out);
    } else {
        modconv_kernel<<<dim3(4, COUT, BB), 256, 0, stream>>>(x, cw, s, scale_p, out);
    }
}